// Round 1
// baseline (2001.610 us; speedup 1.0000x reference)
//
#include <hip/hip_runtime.h>
#include <math.h>

#define NN 100000
#define EE 1000000
#define DD 128
#define CLS 64

// ---------------- PE add: h = x + pe (broadcast over nodes) ----------------
__global__ __launch_bounds__(256) void pe_kernel(const float* __restrict__ x,
                                                 const float* __restrict__ pe,
                                                 float* __restrict__ h) {
  int idx4 = blockIdx.x * 256 + threadIdx.x;   // float4 index, grid exact
  float4 xv = ((const float4*)x)[idx4];
  int d0 = (idx4 & 31) * 4;                    // feature offset 0..124
  float4 pv = *(const float4*)&pe[d0];
  float4 o;
  o.x = xv.x + pv.x; o.y = xv.y + pv.y; o.z = xv.z + pv.z; o.w = xv.w + pv.w;
  ((float4*)h)[idx4] = o;
}

// ---------------- CSR build: histogram ----------------
__global__ __launch_bounds__(256) void hist_kernel(const int* __restrict__ ei0,
                                                   const int* __restrict__ ei1,
                                                   const int* __restrict__ ei2,
                                                   int* __restrict__ counts) {
  int eg = blockIdx.x * 256 + threadIdx.x;
  if (eg >= 3 * EE) return;
  int view = eg / EE;
  int e = eg - view * EE;
  const int* ei = (view == 0) ? ei0 : (view == 1) ? ei1 : ei2;
  int dst = ei[EE + e];                        // row 1 = destination
  atomicAdd(&counts[view * NN + dst], 1);
}

// ---------------- scan (exclusive prefix over 3N counts) ----------------
__global__ __launch_bounds__(256) void scan1_kernel(const int* __restrict__ counts,
                                                    int* __restrict__ offs,
                                                    int* __restrict__ bsums) {
  __shared__ int sd[256];
  int t = threadIdx.x;
  int base = blockIdx.x * 1024 + t * 4;
  int4 v = make_int4(0, 0, 0, 0);
  if (base + 3 < 3 * NN) {
    v = *(const int4*)&counts[base];
  } else {
    if (base + 0 < 3 * NN) v.x = counts[base + 0];
    if (base + 1 < 3 * NN) v.y = counts[base + 1];
    if (base + 2 < 3 * NN) v.z = counts[base + 2];
    if (base + 3 < 3 * NN) v.w = counts[base + 3];
  }
  int ts = v.x + v.y + v.z + v.w;
  sd[t] = ts;
  __syncthreads();
  for (int off = 1; off < 256; off <<= 1) {
    int xel = (t >= off) ? sd[t - off] : 0;
    __syncthreads();
    sd[t] += xel;
    __syncthreads();
  }
  int excl = sd[t] - ts;
  int o0 = excl, o1 = o0 + v.x, o2 = o1 + v.y, o3 = o2 + v.z;
  if (base + 0 < 3 * NN) offs[base + 0] = o0;
  if (base + 1 < 3 * NN) offs[base + 1] = o1;
  if (base + 2 < 3 * NN) offs[base + 2] = o2;
  if (base + 3 < 3 * NN) offs[base + 3] = o3;
  if (t == 255) bsums[blockIdx.x] = sd[255];
}

__global__ void scan2_kernel(int* __restrict__ bsums, int nb) {
  __shared__ int sd[512];
  int t = threadIdx.x;
  int v = (t < nb) ? bsums[t] : 0;
  sd[t] = v;
  __syncthreads();
  for (int off = 1; off < 512; off <<= 1) {
    int xel = (t >= off) ? sd[t - off] : 0;
    __syncthreads();
    sd[t] += xel;
    __syncthreads();
  }
  if (t < nb) bsums[t] = sd[t] - v;   // exclusive block base
}

__global__ __launch_bounds__(256) void scan3_kernel(int* __restrict__ offs,
                                                    const int* __restrict__ bsums) {
  int i = blockIdx.x * 256 + threadIdx.x;
  if (i < 3 * NN) offs[i] += bsums[i >> 10];
  if (i == 0) offs[3 * NN] = 3 * EE;
}

// ---------------- CSR fill ----------------
__global__ __launch_bounds__(256) void fill_kernel(const int* __restrict__ ei0,
                                                   const int* __restrict__ ei1,
                                                   const int* __restrict__ ei2,
                                                   const float* __restrict__ ew0,
                                                   const float* __restrict__ ew1,
                                                   const float* __restrict__ ew2,
                                                   const int* __restrict__ offs,
                                                   int* __restrict__ cursor,
                                                   int* __restrict__ csr_src,
                                                   float* __restrict__ csr_w) {
  int eg = blockIdx.x * 256 + threadIdx.x;
  if (eg >= 3 * EE) return;
  int view = eg / EE;
  int e = eg - view * EE;
  const int* ei = (view == 0) ? ei0 : (view == 1) ? ei1 : ei2;
  const float* ew = (view == 0) ? ew0 : (view == 1) ? ew1 : ew2;
  int src = ei[e];
  int dst = ei[EE + e];
  int key = view * NN + dst;
  int pos = offs[key] + atomicAdd(&cursor[key], 1);
  csr_src[pos] = src;
  csr_w[pos] = ew[e];
}

// ---------------- GEMM: out[i][j] = sum_k H[i][k] * (Wa[j][k] (+ Wb[j][k])) ----------------
// 64-row x 128-col tile per block, k chunked by 64 so LDS <= 64 KB.
__global__ __launch_bounds__(256) void mm_kernel(const float* __restrict__ H,
                                                 const float* __restrict__ Wa,
                                                 const float* __restrict__ Wb,
                                                 float* __restrict__ out) {
  __shared__ float Wt[64 * 132];  // Wt[k][j], pad 132 kills write conflicts
  __shared__ float Ht[64 * 68];   // Ht[k][i], pad 68
  int tid = threadIdx.x;
  int rowbase = blockIdx.x * 64;
  int j0 = (tid & 31) * 4;
  int i0 = (tid >> 5) * 4;
  float acc[8][4];
#pragma unroll
  for (int r = 0; r < 8; ++r)
#pragma unroll
    for (int c = 0; c < 4; ++c) acc[r][c] = 0.f;
  const bool hasWb = (Wb != nullptr);

  for (int kk = 0; kk < 128; kk += 64) {
    for (int idx = tid; idx < 128 * 64; idx += 256) {
      int j = idx >> 6, k = idx & 63;
      float w = Wa[j * 128 + kk + k];
      if (hasWb) w += Wb[j * 128 + kk + k];
      Wt[k * 132 + j] = w;
    }
    for (int idx = tid; idx < 64 * 64; idx += 256) {
      int i = idx >> 6, k = idx & 63;
      int r = rowbase + i;
      if (r >= NN) r = NN - 1;                // clamp (tail block), stores masked
      Ht[k * 68 + i] = H[r * 128 + kk + k];
    }
    __syncthreads();
#pragma unroll 8
    for (int k = 0; k < 64; ++k) {
      float4 a0 = *(const float4*)&Ht[k * 68 + i0];
      float4 a1 = *(const float4*)&Ht[k * 68 + i0 + 32];
      float4 b = *(const float4*)&Wt[k * 132 + j0];
      float ar[8] = {a0.x, a0.y, a0.z, a0.w, a1.x, a1.y, a1.z, a1.w};
      float br[4] = {b.x, b.y, b.z, b.w};
#pragma unroll
      for (int r = 0; r < 8; ++r)
#pragma unroll
        for (int c = 0; c < 4; ++c) acc[r][c] += ar[r] * br[c];
    }
    __syncthreads();
  }
#pragma unroll
  for (int rr = 0; rr < 8; ++rr) {
    int i = (rr < 4) ? (i0 + rr) : (32 + i0 + rr - 4);
    int row = rowbase + i;
    if (row < NN) {
      float4 o = make_float4(acc[rr][0], acc[rr][1], acc[rr][2], acc[rr][3]);
      *(float4*)&out[row * 128 + j0] = o;
    }
  }
}

// ---------------- gather-aggregate + combine + residual + leaky_relu ----------------
// one wave per node, each lane owns 2 features (float2)
__global__ __launch_bounds__(256) void agg_kernel(
    const float* __restrict__ t_in, const float* __restrict__ t_out,
    const float* __restrict__ t_und, const int* __restrict__ csr_src,
    const float* __restrict__ csr_w, const int* __restrict__ offs,
    const float* __restrict__ h_prev, const float* __restrict__ b_mi,
    const float* __restrict__ b_mo, const float* __restrict__ b_si,
    const float* __restrict__ b_so, const float* __restrict__ b_u,
    const float* __restrict__ Cin, const float* __restrict__ Cout,
    const float* __restrict__ Call, const float* __restrict__ cst,
    float* __restrict__ h_out) {
  int gid = blockIdx.x * 256 + threadIdx.x;
  int v = gid >> 6;        // grid exact: 25000 blocks * 4 waves = 100000 nodes
  int lane = gid & 63;
  int f0 = lane * 2;
  float2 aI = {0.f, 0.f}, aO = {0.f, 0.f}, aU = {0.f, 0.f};

  int s = offs[v], e = offs[v + 1];
  for (int i = s; i < e; ++i) {
    int src = csr_src[i];
    float w = csr_w[i];
    float2 tv = *(const float2*)&t_in[src * 128 + f0];
    aI.x += w * tv.x; aI.y += w * tv.y;
  }
  s = offs[NN + v]; e = offs[NN + v + 1];
  for (int i = s; i < e; ++i) {
    int src = csr_src[i];
    float w = csr_w[i];
    float2 tv = *(const float2*)&t_out[src * 128 + f0];
    aO.x += w * tv.x; aO.y += w * tv.y;
  }
  s = offs[2 * NN + v]; e = offs[2 * NN + v + 1];
  for (int i = s; i < e; ++i) {
    int src = csr_src[i];
    float w = csr_w[i];
    float2 tv = *(const float2*)&t_und[src * 128 + f0];
    aU.x += w * tv.x; aU.y += w * tv.y;
  }

  float ci = Cin[v], co = Cout[v], ca = Call[v];
  float2 bi = *(const float2*)&b_mi[f0];
  float2 bsi2 = *(const float2*)&b_si[f0];
  float2 bo = *(const float2*)&b_mo[f0];
  float2 bso2 = *(const float2*)&b_so[f0];
  float2 bu = *(const float2*)&b_u[f0];
  float2 cs = *(const float2*)&cst[v * 128 + f0];
  float2 hp = *(const float2*)&h_prev[v * 128 + f0];

  float gx = ca * (aU.x + bu.x) + ci * (aI.x + bi.x + bsi2.x) +
             co * (aO.x + bo.x + bso2.x) + cs.x + hp.x;
  float gy = ca * (aU.y + bu.y) + ci * (aI.y + bi.y + bsi2.y) +
             co * (aO.y + bo.y + bso2.y) + cs.y + hp.y;
  float2 o;
  o.x = gx > 0.f ? gx : 0.01f * gx;
  o.y = gy > 0.f ? gy : 0.01f * gy;
  *(float2*)&h_out[v * 128 + f0] = o;
}

// ---------------- fused decoder: z=relu(hWd1^T+b1), logits, log_softmax, emb ----------------
// 32 nodes per block; wave w owns rows {w, w+4, ..., w+28}; lane = class index.
__global__ __launch_bounds__(256) void dec_kernel(const float* __restrict__ h,
                                                  const float* __restrict__ Wd1,
                                                  const float* __restrict__ bd1,
                                                  const float* __restrict__ Wd2,
                                                  const float* __restrict__ bd2,
                                                  float* __restrict__ out_logp,
                                                  float* __restrict__ out_emb) {
  __shared__ float Hs[32 * 128];
  __shared__ float W1t[64 * 66];  // W1t[k][j] transposed chunk (64 k at a time)
  __shared__ float W2t[64 * 66];  // W2t[k][c]
  __shared__ float Zs[32 * 68];
  int tid = threadIdx.x;
  int base = blockIdx.x * 32;

  for (int idx = tid; idx < 4096; idx += 256) Hs[idx] = h[base * 128 + idx];
  for (int idx = tid; idx < 4096; idx += 256) {
    int c = idx >> 6, k = idx & 63;
    W2t[k * 66 + c] = Wd2[idx];
  }

  int j = tid & 63;
  int rg = tid >> 6;
  float zacc[8];
#pragma unroll
  for (int r = 0; r < 8; ++r) zacc[r] = 0.f;

  for (int kk = 0; kk < 128; kk += 64) {
    __syncthreads();
    for (int idx = tid; idx < 4096; idx += 256) {
      int jj = idx >> 6, k = idx & 63;
      W1t[k * 66 + jj] = Wd1[jj * 128 + kk + k];
    }
    __syncthreads();
    for (int k = 0; k < 64; ++k) {
      float w = W1t[k * 66 + j];
#pragma unroll
      for (int r = 0; r < 8; ++r) zacc[r] += Hs[(rg * 8 + r) * 128 + kk + k] * w;
    }
  }
  float b1 = bd1[j];
#pragma unroll
  for (int r = 0; r < 8; ++r) {
    float z = zacc[r] + b1;
    Zs[(rg * 8 + r) * 68 + j] = z > 0.f ? z : 0.f;
  }
  __syncthreads();

  float b2 = bd2[j];
  float lg[8];
#pragma unroll
  for (int i = 0; i < 8; ++i) lg[i] = b2;
  for (int k = 0; k < 64; ++k) {
    float w = W2t[k * 66 + j];
#pragma unroll
    for (int i = 0; i < 8; ++i) lg[i] += Zs[(rg + 4 * i) * 68 + k] * w;
  }

#pragma unroll
  for (int i = 0; i < 8; ++i) {
    float m = lg[i];
    for (int d = 1; d < 64; d <<= 1) m = fmaxf(m, __shfl_xor(m, d));
    float s = expf(lg[i] - m);
    for (int d = 1; d < 64; d <<= 1) s += __shfl_xor(s, d);
    float lp = lg[i] - m - logf(s);
    out_logp[(base + rg + 4 * i) * 64 + j] = lp;
  }

#pragma unroll
  for (int i = 0; i < 8; ++i) {
    int r = rg + 4 * i;
    float v1 = Hs[r * 128 + j];
    float v2 = Hs[r * 128 + 64 + j];
    float ss = v1 * v1 + v2 * v2;
    for (int d = 1; d < 64; d <<= 1) ss += __shfl_xor(ss, d);
    float nrm = sqrtf(ss);
    float sc = 1.f / fmaxf(nrm, 1e-12f);
    int o = (base + r) * 128;
    out_emb[o + j] = v1 * sc;
    out_emb[o + 64 + j] = v2 * sc;
  }
}

extern "C" void kernel_launch(void* const* d_in, const int* in_sizes, int n_in,
                              void* d_out, int out_size, void* d_ws, size_t ws_size,
                              hipStream_t stream) {
  const float* x   = (const float*)d_in[0];
  const int* eiI   = (const int*)d_in[1];
  const float* ewI = (const float*)d_in[2];
  const int* eiO   = (const int*)d_in[3];
  const float* ewO = (const float*)d_in[4];
  const int* eiU   = (const int*)d_in[5];
  const float* ewU = (const float*)d_in[6];
  const float* pe  = (const float*)d_in[7];
  const float* Wmi = (const float*)d_in[8];
  const float* Wmo = (const float*)d_in[9];
  const float* Wsh = (const float*)d_in[10];
  const float* Wu  = (const float*)d_in[11];
  const float* bmi = (const float*)d_in[12];
  const float* bmo = (const float*)d_in[13];
  const float* bsi = (const float*)d_in[14];
  const float* bso = (const float*)d_in[15];
  const float* bu  = (const float*)d_in[16];
  const float* Cin = (const float*)d_in[17];
  const float* Cou = (const float*)d_in[18];
  const float* Cal = (const float*)d_in[19];
  const float* cst = (const float*)d_in[20];
  const float* Wd1 = (const float*)d_in[21];
  const float* bd1 = (const float*)d_in[22];
  const float* Wd2 = (const float*)d_in[23];
  const float* bd2 = (const float*)d_in[24];

  const size_t ND = (size_t)NN * DD;
  float* ws = (float*)d_ws;
  size_t off = 0;
  float* hA = ws + off;   off += ND;
  float* hB = ws + off;   off += ND;
  float* tIn = ws + off;  off += ND;
  float* tOut = ws + off; off += ND;
  float* tUnd = ws + off; off += ND;
  float* csrW = ws + off; off += (size_t)3 * EE;
  int* csrS   = (int*)(ws + off);
  int* counts = csrS + (size_t)3 * EE;   // 3N (zeroed)
  int* cursor = counts + 3 * NN;         // 3N (zeroed)
  int* offs   = cursor + 3 * NN;         // 3N+1 (+pad)
  int* bsums  = offs + 3 * NN + 4;       // block sums for scan

  hipMemsetAsync(counts, 0, (size_t)6 * NN * sizeof(int), stream);

  pe_kernel<<<12500, 256, 0, stream>>>(x, pe, hA);
  hist_kernel<<<(3 * EE + 255) / 256, 256, 0, stream>>>(eiI, eiO, eiU, counts);
  const int nb1 = (3 * NN + 1023) / 1024;  // 293
  scan1_kernel<<<nb1, 256, 0, stream>>>(counts, offs, bsums);
  scan2_kernel<<<1, 512, 0, stream>>>(bsums, nb1);
  scan3_kernel<<<(3 * NN + 255) / 256, 256, 0, stream>>>(offs, bsums);
  fill_kernel<<<(3 * EE + 255) / 256, 256, 0, stream>>>(eiI, eiO, eiU, ewI, ewO, ewU,
                                                        offs, cursor, csrS, csrW);

  const float* hin = hA;
  float* hout = hB;
  const int mmGrid = (NN + 63) / 64;  // 1563
  for (int l = 0; l < 2; ++l) {
    const float* Wl_mi = Wmi + l * DD * DD;
    const float* Wl_mo = Wmo + l * DD * DD;
    const float* Wl_sh = Wsh + l * DD * DD;
    const float* Wl_u  = Wu + l * DD * DD;
    mm_kernel<<<mmGrid, 256, 0, stream>>>(hin, Wl_mi, Wl_sh, tIn);
    mm_kernel<<<mmGrid, 256, 0, stream>>>(hin, Wl_mo, Wl_sh, tOut);
    mm_kernel<<<mmGrid, 256, 0, stream>>>(hin, Wl_u, nullptr, tUnd);
    agg_kernel<<<25000, 256, 0, stream>>>(tIn, tOut, tUnd, csrS, csrW, offs, hin,
                                          bmi + l * DD, bmo + l * DD, bsi + l * DD,
                                          bso + l * DD, bu + l * DD, Cin + l * NN,
                                          Cou + l * NN, Cal + l * NN,
                                          cst + (size_t)l * NN * DD, hout);
    float* tmp = (float*)hin;
    hin = hout;
    hout = tmp;
  }

  float* out_logp = (float*)d_out;
  float* out_emb = out_logp + (size_t)NN * CLS;
  dec_kernel<<<3125, 256, 0, stream>>>(hin, Wd1, bd1, Wd2, bd2, out_logp, out_emb);
}

// Round 2
// 1160.621 us; speedup vs baseline: 1.7246x; 1.7246x over previous
//
#include <hip/hip_runtime.h>
#include <math.h>

#define NN 100000
#define EE 1000000
#define DD 128
#define CLS 64

typedef short bf16x8 __attribute__((ext_vector_type(8)));
typedef float f32x4 __attribute__((ext_vector_type(4)));

static __device__ __forceinline__ short f2bf(float f) {
  union { float f; unsigned u; } v; v.f = f;
  unsigned r = v.u + 0x7FFF + ((v.u >> 16) & 1);   // RNE
  return (short)(r >> 16);
}
static __device__ __forceinline__ float bf_lo(unsigned u) {
  union { unsigned u; float f; } v; v.u = u << 16; return v.f;
}
static __device__ __forceinline__ float bf_hi(unsigned u) {
  union { unsigned u; float f; } v; v.u = u & 0xffff0000u; return v.f;
}

// ---------------- PE add: h = x + pe ----------------
__global__ __launch_bounds__(256) void pe_kernel(const float* __restrict__ x,
                                                 const float* __restrict__ pe,
                                                 float* __restrict__ h) {
  int idx4 = blockIdx.x * 256 + threadIdx.x;
  float4 xv = ((const float4*)x)[idx4];
  int d0 = (idx4 & 31) * 4;
  float4 pv = *(const float4*)&pe[d0];
  float4 o;
  o.x = xv.x + pv.x; o.y = xv.y + pv.y; o.z = xv.z + pv.z; o.w = xv.w + pv.w;
  ((float4*)h)[idx4] = o;
}

// ---------------- weight prep: Wcat[l][j][k] bf16, j<128: Wmi+Wsh, <256: Wmo+Wsh, else Wu ----
__global__ __launch_bounds__(256) void wprep_kernel(const float* __restrict__ Wmi,
                                                    const float* __restrict__ Wmo,
                                                    const float* __restrict__ Wsh,
                                                    const float* __restrict__ Wu,
                                                    short* __restrict__ Wcat) {
  int idx = blockIdx.x * 256 + threadIdx.x;   // grid 384 -> 98304 exact
  int l = idx / 49152;
  int r = idx - l * 49152;
  int j = r >> 7, k = r & 127;
  float v;
  if (j < 128)      v = Wmi[l*16384 + j*128 + k] + Wsh[l*16384 + j*128 + k];
  else if (j < 256) v = Wmo[l*16384 + (j-128)*128 + k] + Wsh[l*16384 + (j-128)*128 + k];
  else              v = Wu[l*16384 + (j-256)*128 + k];
  Wcat[idx] = f2bf(v);
}

// ---------------- CSR build: histogram ----------------
__global__ __launch_bounds__(256) void hist_kernel(const int* __restrict__ ei0,
                                                   const int* __restrict__ ei1,
                                                   const int* __restrict__ ei2,
                                                   int* __restrict__ counts) {
  int eg = blockIdx.x * 256 + threadIdx.x;
  if (eg >= 3 * EE) return;
  int view = eg / EE;
  int e = eg - view * EE;
  const int* ei = (view == 0) ? ei0 : (view == 1) ? ei1 : ei2;
  int dst = ei[EE + e];
  atomicAdd(&counts[view * NN + dst], 1);
}

// ---------------- scan ----------------
__global__ __launch_bounds__(256) void scan1_kernel(const int* __restrict__ counts,
                                                    int* __restrict__ offs,
                                                    int* __restrict__ bsums) {
  __shared__ int sd[256];
  int t = threadIdx.x;
  int base = blockIdx.x * 1024 + t * 4;
  int4 v = make_int4(0, 0, 0, 0);
  if (base + 3 < 3 * NN) {
    v = *(const int4*)&counts[base];
  } else {
    if (base + 0 < 3 * NN) v.x = counts[base + 0];
    if (base + 1 < 3 * NN) v.y = counts[base + 1];
    if (base + 2 < 3 * NN) v.z = counts[base + 2];
    if (base + 3 < 3 * NN) v.w = counts[base + 3];
  }
  int ts = v.x + v.y + v.z + v.w;
  sd[t] = ts;
  __syncthreads();
  for (int off = 1; off < 256; off <<= 1) {
    int xel = (t >= off) ? sd[t - off] : 0;
    __syncthreads();
    sd[t] += xel;
    __syncthreads();
  }
  int excl = sd[t] - ts;
  int o0 = excl, o1 = o0 + v.x, o2 = o1 + v.y, o3 = o2 + v.z;
  if (base + 0 < 3 * NN) offs[base + 0] = o0;
  if (base + 1 < 3 * NN) offs[base + 1] = o1;
  if (base + 2 < 3 * NN) offs[base + 2] = o2;
  if (base + 3 < 3 * NN) offs[base + 3] = o3;
  if (t == 255) bsums[blockIdx.x] = sd[255];
}

__global__ void scan2_kernel(int* __restrict__ bsums, int nb) {
  __shared__ int sd[512];
  int t = threadIdx.x;
  int v = (t < nb) ? bsums[t] : 0;
  sd[t] = v;
  __syncthreads();
  for (int off = 1; off < 512; off <<= 1) {
    int xel = (t >= off) ? sd[t - off] : 0;
    __syncthreads();
    sd[t] += xel;
    __syncthreads();
  }
  if (t < nb) bsums[t] = sd[t] - v;
}

__global__ __launch_bounds__(256) void scan3_kernel(int* __restrict__ offs,
                                                    const int* __restrict__ bsums) {
  int i = blockIdx.x * 256 + threadIdx.x;
  if (i < 3 * NN) offs[i] += bsums[i >> 10];
  if (i == 0) offs[3 * NN] = 3 * EE;
}

// ---------------- CSR fill (packed int2 records) ----------------
__global__ __launch_bounds__(256) void fill_kernel(const int* __restrict__ ei0,
                                                   const int* __restrict__ ei1,
                                                   const int* __restrict__ ei2,
                                                   const float* __restrict__ ew0,
                                                   const float* __restrict__ ew1,
                                                   const float* __restrict__ ew2,
                                                   const int* __restrict__ offs,
                                                   int* __restrict__ cursor,
                                                   int2* __restrict__ csrE) {
  int eg = blockIdx.x * 256 + threadIdx.x;
  if (eg >= 3 * EE) return;
  int view = eg / EE;
  int e = eg - view * EE;
  const int* ei = (view == 0) ? ei0 : (view == 1) ? ei1 : ei2;
  const float* ew = (view == 0) ? ew0 : (view == 1) ? ew1 : ew2;
  int src = ei[e];
  int dst = ei[EE + e];
  int key = view * NN + dst;
  int pos = offs[key] + atomicAdd(&cursor[key], 1);
  csrE[pos] = make_int2(src, __float_as_int(ew[e]));
}

// ---------------- fused 3-view GEMM via bf16 MFMA ----------------
// grid (782, 3): 128-row tile x one 128-col view. out[i][j] = sum_k H[i][k]*Wcat[view*128+j][k]
#define LW 136   // padded LDS row stride (shorts): 272 B, 16B aligned, free 2-way banks
__global__ __launch_bounds__(256) void mm_mfma(const float* __restrict__ H,
                                               const short* __restrict__ WcatL,
                                               short* __restrict__ tIn,
                                               short* __restrict__ tOut,
                                               short* __restrict__ tUnd) {
  __shared__ short As[128 * LW];
  __shared__ short Bs[128 * LW];
  int tid = threadIdx.x;
  int rowbase = blockIdx.x * 128;
  int view = blockIdx.y;

  // stage A: fp32 -> bf16, 4 elems/thread/iter
  for (int idx = tid; idx < 4096; idx += 256) {
    int r = idx >> 5, c4 = (idx & 31) * 4;
    int gr = rowbase + r; if (gr >= NN) gr = NN - 1;
    float4 v = *(const float4*)&H[(size_t)gr * 128 + c4];
    int p0 = ((int)(unsigned short)f2bf(v.y) << 16) | (unsigned short)f2bf(v.x);
    int p1 = ((int)(unsigned short)f2bf(v.w) << 16) | (unsigned short)f2bf(v.z);
    *(int2*)&As[r * LW + c4] = make_int2(p0, p1);
  }
  // stage B: 128 bf16 rows of Wcat for this view, 16B chunks
  for (int idx = tid; idx < 2048; idx += 256) {
    int r = idx >> 4, c8 = (idx & 15) * 8;
    *(int4*)&Bs[r * LW + c8] = *(const int4*)&WcatL[(view * 128 + r) * 128 + c8];
  }
  __syncthreads();

  int w = tid >> 6, lane = tid & 63;
  int wr = (w >> 1) * 64, wc = (w & 1) * 64;
  int lrow = lane & 15, quad = lane >> 4;

  f32x4 acc[4][4];
#pragma unroll
  for (int mi = 0; mi < 4; ++mi)
#pragma unroll
    for (int ni = 0; ni < 4; ++ni) acc[mi][ni] = (f32x4){0.f, 0.f, 0.f, 0.f};

#pragma unroll
  for (int k0 = 0; k0 < 128; k0 += 32) {
    bf16x8 a[4], b[4];
#pragma unroll
    for (int mi = 0; mi < 4; ++mi)
      a[mi] = *(const bf16x8*)&As[(wr + mi * 16 + lrow) * LW + k0 + quad * 8];
#pragma unroll
    for (int ni = 0; ni < 4; ++ni)
      b[ni] = *(const bf16x8*)&Bs[(wc + ni * 16 + lrow) * LW + k0 + quad * 8];
#pragma unroll
    for (int mi = 0; mi < 4; ++mi)
#pragma unroll
      for (int ni = 0; ni < 4; ++ni)
        acc[mi][ni] = __builtin_amdgcn_mfma_f32_16x16x32_bf16(a[mi], b[ni], acc[mi][ni], 0, 0, 0);
  }

  short* out = (view == 0) ? tIn : (view == 1) ? tOut : tUnd;
#pragma unroll
  for (int mi = 0; mi < 4; ++mi) {
#pragma unroll
    for (int ni = 0; ni < 4; ++ni) {
#pragma unroll
      for (int r = 0; r < 4; ++r) {
        int row = rowbase + wr + mi * 16 + quad * 4 + r;
        if (row < NN) {
          int col = wc + ni * 16 + lrow;
          out[(size_t)row * 128 + col] = f2bf(acc[mi][ni][r]);
        }
      }
    }
  }
}

// ---------------- gather-aggregate + combine + residual + leaky_relu ----------------
// one wave per node, lane owns 2 bf16 features (4B gather per lane)
__global__ __launch_bounds__(256) void agg_kernel(
    const short* __restrict__ t_in, const short* __restrict__ t_out,
    const short* __restrict__ t_und, const int2* __restrict__ csrE,
    const int* __restrict__ offs, const float* __restrict__ h_prev,
    const float* __restrict__ b_mi, const float* __restrict__ b_mo,
    const float* __restrict__ b_si, const float* __restrict__ b_so,
    const float* __restrict__ b_u, const float* __restrict__ Cin,
    const float* __restrict__ Cout, const float* __restrict__ Call,
    const float* __restrict__ cst, float* __restrict__ h_out) {
  int gid = blockIdx.x * 256 + threadIdx.x;
  int v = gid >> 6;
  int lane = gid & 63;
  int f0 = lane * 2;
  float aIx = 0.f, aIy = 0.f, aOx = 0.f, aOy = 0.f, aUx = 0.f, aUy = 0.f;

  {
    int s = offs[v], e = offs[v + 1];
    int i = s;
    for (; i + 1 < e; i += 2) {
      int2 e0 = csrE[i], e1 = csrE[i + 1];
      unsigned u0 = *(const unsigned*)&t_in[(size_t)e0.x * 128 + f0];
      unsigned u1 = *(const unsigned*)&t_in[(size_t)e1.x * 128 + f0];
      float w0 = __int_as_float(e0.y), w1 = __int_as_float(e1.y);
      aIx += w0 * bf_lo(u0) + w1 * bf_lo(u1);
      aIy += w0 * bf_hi(u0) + w1 * bf_hi(u1);
    }
    if (i < e) {
      int2 e0 = csrE[i];
      unsigned u0 = *(const unsigned*)&t_in[(size_t)e0.x * 128 + f0];
      float w0 = __int_as_float(e0.y);
      aIx += w0 * bf_lo(u0); aIy += w0 * bf_hi(u0);
    }
  }
  {
    int s = offs[NN + v], e = offs[NN + v + 1];
    int i = s;
    for (; i + 1 < e; i += 2) {
      int2 e0 = csrE[i], e1 = csrE[i + 1];
      unsigned u0 = *(const unsigned*)&t_out[(size_t)e0.x * 128 + f0];
      unsigned u1 = *(const unsigned*)&t_out[(size_t)e1.x * 128 + f0];
      float w0 = __int_as_float(e0.y), w1 = __int_as_float(e1.y);
      aOx += w0 * bf_lo(u0) + w1 * bf_lo(u1);
      aOy += w0 * bf_hi(u0) + w1 * bf_hi(u1);
    }
    if (i < e) {
      int2 e0 = csrE[i];
      unsigned u0 = *(const unsigned*)&t_out[(size_t)e0.x * 128 + f0];
      float w0 = __int_as_float(e0.y);
      aOx += w0 * bf_lo(u0); aOy += w0 * bf_hi(u0);
    }
  }
  {
    int s = offs[2 * NN + v], e = offs[2 * NN + v + 1];
    int i = s;
    for (; i + 1 < e; i += 2) {
      int2 e0 = csrE[i], e1 = csrE[i + 1];
      unsigned u0 = *(const unsigned*)&t_und[(size_t)e0.x * 128 + f0];
      unsigned u1 = *(const unsigned*)&t_und[(size_t)e1.x * 128 + f0];
      float w0 = __int_as_float(e0.y), w1 = __int_as_float(e1.y);
      aUx += w0 * bf_lo(u0) + w1 * bf_lo(u1);
      aUy += w0 * bf_hi(u0) + w1 * bf_hi(u1);
    }
    if (i < e) {
      int2 e0 = csrE[i];
      unsigned u0 = *(const unsigned*)&t_und[(size_t)e0.x * 128 + f0];
      float w0 = __int_as_float(e0.y);
      aUx += w0 * bf_lo(u0); aUy += w0 * bf_hi(u0);
    }
  }

  float ci = Cin[v], co = Cout[v], ca = Call[v];
  float2 bi = *(const float2*)&b_mi[f0];
  float2 bsi2 = *(const float2*)&b_si[f0];
  float2 bo = *(const float2*)&b_mo[f0];
  float2 bso2 = *(const float2*)&b_so[f0];
  float2 bu = *(const float2*)&b_u[f0];
  float2 cs = *(const float2*)&cst[(size_t)v * 128 + f0];
  float2 hp = *(const float2*)&h_prev[(size_t)v * 128 + f0];

  float gx = ca * (aUx + bu.x) + ci * (aIx + bi.x + bsi2.x) +
             co * (aOx + bo.x + bso2.x) + cs.x + hp.x;
  float gy = ca * (aUy + bu.y) + ci * (aIy + bi.y + bsi2.y) +
             co * (aOy + bo.y + bso2.y) + cs.y + hp.y;
  float2 o;
  o.x = gx > 0.f ? gx : 0.01f * gx;
  o.y = gy > 0.f ? gy : 0.01f * gy;
  *(float2*)&h_out[(size_t)v * 128 + f0] = o;
}

// ---------------- fused decoder ----------------
__global__ __launch_bounds__(256) void dec_kernel(const float* __restrict__ h,
                                                  const float* __restrict__ Wd1,
                                                  const float* __restrict__ bd1,
                                                  const float* __restrict__ Wd2,
                                                  const float* __restrict__ bd2,
                                                  float* __restrict__ out_logp,
                                                  float* __restrict__ out_emb) {
  __shared__ float Hs[32 * 128];
  __shared__ float W1t[64 * 66];
  __shared__ float W2t[64 * 66];
  __shared__ float Zs[32 * 68];
  int tid = threadIdx.x;
  int base = blockIdx.x * 32;

  for (int idx = tid; idx < 4096; idx += 256) Hs[idx] = h[(size_t)base * 128 + idx];
  for (int idx = tid; idx < 4096; idx += 256) {
    int c = idx >> 6, k = idx & 63;
    W2t[k * 66 + c] = Wd2[idx];
  }

  int j = tid & 63;
  int rg = tid >> 6;
  float zacc[8];
#pragma unroll
  for (int r = 0; r < 8; ++r) zacc[r] = 0.f;

  for (int kk = 0; kk < 128; kk += 64) {
    __syncthreads();
    for (int idx = tid; idx < 4096; idx += 256) {
      int jj = idx >> 6, k = idx & 63;
      W1t[k * 66 + jj] = Wd1[jj * 128 + kk + k];
    }
    __syncthreads();
    for (int k = 0; k < 64; ++k) {
      float w = W1t[k * 66 + j];
#pragma unroll
      for (int r = 0; r < 8; ++r) zacc[r] += Hs[(rg * 8 + r) * 128 + kk + k] * w;
    }
  }
  float b1 = bd1[j];
#pragma unroll
  for (int r = 0; r < 8; ++r) {
    float z = zacc[r] + b1;
    Zs[(rg * 8 + r) * 68 + j] = z > 0.f ? z : 0.f;
  }
  __syncthreads();

  float b2 = bd2[j];
  float lg[8];
#pragma unroll
  for (int i = 0; i < 8; ++i) lg[i] = b2;
  for (int k = 0; k < 64; ++k) {
    float w = W2t[k * 66 + j];
#pragma unroll
    for (int i = 0; i < 8; ++i) lg[i] += Zs[(rg + 4 * i) * 68 + k] * w;
  }

#pragma unroll
  for (int i = 0; i < 8; ++i) {
    float m = lg[i];
    for (int d = 1; d < 64; d <<= 1) m = fmaxf(m, __shfl_xor(m, d));
    float s = expf(lg[i] - m);
    for (int d = 1; d < 64; d <<= 1) s += __shfl_xor(s, d);
    float lp = lg[i] - m - logf(s);
    out_logp[(size_t)(base + rg + 4 * i) * 64 + j] = lp;
  }

#pragma unroll
  for (int i = 0; i < 8; ++i) {
    int r = rg + 4 * i;
    float v1 = Hs[r * 128 + j];
    float v2 = Hs[r * 128 + 64 + j];
    float ss = v1 * v1 + v2 * v2;
    for (int d = 1; d < 64; d <<= 1) ss += __shfl_xor(ss, d);
    float nrm = sqrtf(ss);
    float sc = 1.f / fmaxf(nrm, 1e-12f);
    size_t o = (size_t)(base + r) * 128;
    out_emb[o + j] = v1 * sc;
    out_emb[o + 64 + j] = v2 * sc;
  }
}

extern "C" void kernel_launch(void* const* d_in, const int* in_sizes, int n_in,
                              void* d_out, int out_size, void* d_ws, size_t ws_size,
                              hipStream_t stream) {
  const float* x   = (const float*)d_in[0];
  const int* eiI   = (const int*)d_in[1];
  const float* ewI = (const float*)d_in[2];
  const int* eiO   = (const int*)d_in[3];
  const float* ewO = (const float*)d_in[4];
  const int* eiU   = (const int*)d_in[5];
  const float* ewU = (const float*)d_in[6];
  const float* pe  = (const float*)d_in[7];
  const float* Wmi = (const float*)d_in[8];
  const float* Wmo = (const float*)d_in[9];
  const float* Wsh = (const float*)d_in[10];
  const float* Wu  = (const float*)d_in[11];
  const float* bmi = (const float*)d_in[12];
  const float* bmo = (const float*)d_in[13];
  const float* bsi = (const float*)d_in[14];
  const float* bso = (const float*)d_in[15];
  const float* bu  = (const float*)d_in[16];
  const float* Cin = (const float*)d_in[17];
  const float* Cou = (const float*)d_in[18];
  const float* Cal = (const float*)d_in[19];
  const float* cst = (const float*)d_in[20];
  const float* Wd1 = (const float*)d_in[21];
  const float* bd1 = (const float*)d_in[22];
  const float* Wd2 = (const float*)d_in[23];
  const float* bd2 = (const float*)d_in[24];

  const size_t ND = (size_t)NN * DD;   // 12,800,000
  float* ws = (float*)d_ws;
  float* hA = ws;
  float* hB = hA + ND;
  short* tIn  = (short*)(hB + ND);
  short* tOut = tIn + ND;
  short* tUnd = tOut + ND;
  short* Wcat = tUnd + ND;                     // 2*384*128 = 98304 shorts
  int2* csrE  = (int2*)(Wcat + 98304);         // 3E records (byte offset /8 OK)
  int* counts = (int*)(csrE + (size_t)3 * EE); // 3N
  int* cursor = counts + 3 * NN;               // 3N
  int* offs   = cursor + 3 * NN;               // 3N+1
  int* bsums  = offs + 3 * NN + 4;

  hipMemsetAsync(counts, 0, (size_t)6 * NN * sizeof(int), stream);

  pe_kernel<<<12500, 256, 0, stream>>>(x, pe, hA);
  wprep_kernel<<<384, 256, 0, stream>>>(Wmi, Wmo, Wsh, Wu, Wcat);
  hist_kernel<<<(3 * EE + 255) / 256, 256, 0, stream>>>(eiI, eiO, eiU, counts);
  const int nb1 = (3 * NN + 1023) / 1024;  // 293
  scan1_kernel<<<nb1, 256, 0, stream>>>(counts, offs, bsums);
  scan2_kernel<<<1, 512, 0, stream>>>(bsums, nb1);
  scan3_kernel<<<(3 * NN + 255) / 256, 256, 0, stream>>>(offs, bsums);
  fill_kernel<<<(3 * EE + 255) / 256, 256, 0, stream>>>(eiI, eiO, eiU, ewI, ewO, ewU,
                                                        offs, cursor, csrE);

  const float* hin = hA;
  float* hout = hB;
  dim3 mmGrid((NN + 127) / 128, 3);  // (782, 3)
  for (int l = 0; l < 2; ++l) {
    mm_mfma<<<mmGrid, 256, 0, stream>>>(hin, Wcat + l * 49152, tIn, tOut, tUnd);
    agg_kernel<<<25000, 256, 0, stream>>>(tIn, tOut, tUnd, csrE, offs, hin,
                                          bmi + l * DD, bmo + l * DD, bsi + l * DD,
                                          bso + l * DD, bu + l * DD, Cin + l * NN,
                                          Cou + l * NN, Cal + l * NN,
                                          cst + (size_t)l * NN * DD, hout);
    float* tmp = (float*)hin;
    hin = hout;
    hout = tmp;
  }

  float* out_logp = (float*)d_out;
  float* out_emb = out_logp + (size_t)NN * CLS;
  dec_kernel<<<3125, 256, 0, stream>>>(hin, Wd1, bd1, Wd2, bd2, out_logp, out_emb);
}

// Round 3
// 1060.387 us; speedup vs baseline: 1.8876x; 1.0945x over previous
//
#include <hip/hip_runtime.h>
#include <math.h>

#define NN 100000
#define EE 1000000
#define DD 128
#define CLS 64

typedef short bf16x8 __attribute__((ext_vector_type(8)));
typedef float f32x4 __attribute__((ext_vector_type(4)));

static __device__ __forceinline__ short f2bf(float f) {
  union { float f; unsigned u; } v; v.f = f;
  unsigned r = v.u + 0x7FFF + ((v.u >> 16) & 1);   // RNE
  return (short)(r >> 16);
}
static __device__ __forceinline__ unsigned pack2(float a, float b) {
  return ((unsigned)(unsigned short)f2bf(b) << 16) | (unsigned short)f2bf(a);
}
static __device__ __forceinline__ float bf_lo(unsigned u) {
  union { unsigned u; float f; } v; v.u = u << 16; return v.f;
}
static __device__ __forceinline__ float bf_hi(unsigned u) {
  union { unsigned u; float f; } v; v.u = u & 0xffff0000u; return v.f;
}

// ---------------- PE add: h = bf16(x + pe), 8 elems/thread ----------------
__global__ __launch_bounds__(256) void pe_kernel(const float* __restrict__ x,
                                                 const float* __restrict__ pe,
                                                 short* __restrict__ h) {
  int idx8 = blockIdx.x * 256 + threadIdx.x;   // grid 6250 -> 1.6M exact
  int d0 = (idx8 & 15) * 8;
  float4 a = *(const float4*)&x[(size_t)idx8 * 8];
  float4 b = *(const float4*)&x[(size_t)idx8 * 8 + 4];
  float4 pa = *(const float4*)&pe[d0];
  float4 pb = *(const float4*)&pe[d0 + 4];
  int4 o;
  o.x = pack2(a.x + pa.x, a.y + pa.y);
  o.y = pack2(a.z + pa.z, a.w + pa.w);
  o.z = pack2(b.x + pb.x, b.y + pb.y);
  o.w = pack2(b.z + pb.z, b.w + pb.w);
  *(int4*)&h[(size_t)idx8 * 8] = o;
}

// ---------------- weight prep ----------------
__global__ __launch_bounds__(256) void wprep_kernel(const float* __restrict__ Wmi,
                                                    const float* __restrict__ Wmo,
                                                    const float* __restrict__ Wsh,
                                                    const float* __restrict__ Wu,
                                                    short* __restrict__ Wcat) {
  int idx = blockIdx.x * 256 + threadIdx.x;   // grid 384 -> 98304 exact
  int l = idx / 49152;
  int r = idx - l * 49152;
  int j = r >> 7, k = r & 127;
  float v;
  if (j < 128)      v = Wmi[l*16384 + j*128 + k] + Wsh[l*16384 + j*128 + k];
  else if (j < 256) v = Wmo[l*16384 + (j-128)*128 + k] + Wsh[l*16384 + (j-128)*128 + k];
  else              v = Wu[l*16384 + (j-256)*128 + k];
  Wcat[idx] = f2bf(v);
}

// ---------------- CSR build: histogram ----------------
__global__ __launch_bounds__(256) void hist_kernel(const int* __restrict__ ei0,
                                                   const int* __restrict__ ei1,
                                                   const int* __restrict__ ei2,
                                                   int* __restrict__ counts) {
  int eg = blockIdx.x * 256 + threadIdx.x;
  if (eg >= 3 * EE) return;
  int view = eg / EE;
  int e = eg - view * EE;
  const int* ei = (view == 0) ? ei0 : (view == 1) ? ei1 : ei2;
  int dst = ei[EE + e];
  atomicAdd(&counts[view * NN + dst], 1);
}

// ---------------- scan ----------------
__global__ __launch_bounds__(256) void scan1_kernel(const int* __restrict__ counts,
                                                    int* __restrict__ offs,
                                                    int* __restrict__ bsums) {
  __shared__ int sd[256];
  int t = threadIdx.x;
  int base = blockIdx.x * 1024 + t * 4;
  int4 v = make_int4(0, 0, 0, 0);
  if (base + 3 < 3 * NN) {
    v = *(const int4*)&counts[base];
  } else {
    if (base + 0 < 3 * NN) v.x = counts[base + 0];
    if (base + 1 < 3 * NN) v.y = counts[base + 1];
    if (base + 2 < 3 * NN) v.z = counts[base + 2];
    if (base + 3 < 3 * NN) v.w = counts[base + 3];
  }
  int ts = v.x + v.y + v.z + v.w;
  sd[t] = ts;
  __syncthreads();
  for (int off = 1; off < 256; off <<= 1) {
    int xel = (t >= off) ? sd[t - off] : 0;
    __syncthreads();
    sd[t] += xel;
    __syncthreads();
  }
  int excl = sd[t] - ts;
  int o0 = excl, o1 = o0 + v.x, o2 = o1 + v.y, o3 = o2 + v.z;
  if (base + 0 < 3 * NN) offs[base + 0] = o0;
  if (base + 1 < 3 * NN) offs[base + 1] = o1;
  if (base + 2 < 3 * NN) offs[base + 2] = o2;
  if (base + 3 < 3 * NN) offs[base + 3] = o3;
  if (t == 255) bsums[blockIdx.x] = sd[255];
}

__global__ void scan2_kernel(int* __restrict__ bsums, int nb) {
  __shared__ int sd[512];
  int t = threadIdx.x;
  int v = (t < nb) ? bsums[t] : 0;
  sd[t] = v;
  __syncthreads();
  for (int off = 1; off < 512; off <<= 1) {
    int xel = (t >= off) ? sd[t - off] : 0;
    __syncthreads();
    sd[t] += xel;
    __syncthreads();
  }
  if (t < nb) bsums[t] = sd[t] - v;
}

__global__ __launch_bounds__(256) void scan3_kernel(int* __restrict__ offs,
                                                    int* __restrict__ work,
                                                    const int* __restrict__ bsums) {
  int i = blockIdx.x * 256 + threadIdx.x;
  if (i < 3 * NN) {
    int v = offs[i] + bsums[i >> 10];
    offs[i] = v;
    work[i] = v;
  }
  if (i == 0) offs[3 * NN] = 3 * EE;
}

// ---------------- CSR fill (single atomic on working offsets) ----------------
__global__ __launch_bounds__(256) void fill_kernel(const int* __restrict__ ei0,
                                                   const int* __restrict__ ei1,
                                                   const int* __restrict__ ei2,
                                                   const float* __restrict__ ew0,
                                                   const float* __restrict__ ew1,
                                                   const float* __restrict__ ew2,
                                                   int* __restrict__ work,
                                                   int2* __restrict__ csrE) {
  int eg = blockIdx.x * 256 + threadIdx.x;
  if (eg >= 3 * EE) return;
  int view = eg / EE;
  int e = eg - view * EE;
  const int* ei = (view == 0) ? ei0 : (view == 1) ? ei1 : ei2;
  const float* ew = (view == 0) ? ew0 : (view == 1) ? ew1 : ew2;
  int src = ei[e];
  int dst = ei[EE + e];
  int pos = atomicAdd(&work[view * NN + dst], 1);
  csrE[pos] = make_int2(src, __float_as_int(ew[e]));
}

// ---------------- fused 3-view GEMM via bf16 MFMA ----------------
#define LW 136
__global__ __launch_bounds__(256) void mm_mfma(const short* __restrict__ H,
                                               const short* __restrict__ WcatL,
                                               short* __restrict__ tAll) {
  __shared__ short As[128 * LW];
  __shared__ short Bs[128 * LW];
  int tid = threadIdx.x;
  int rowbase = blockIdx.x * 128;
  int view = blockIdx.y;

  for (int idx = tid; idx < 2048; idx += 256) {
    int r = idx >> 4, c8 = (idx & 15) * 8;
    int gr = rowbase + r; if (gr >= NN) gr = NN - 1;
    *(int4*)&As[r * LW + c8] = *(const int4*)&H[(size_t)gr * 128 + c8];
  }
  for (int idx = tid; idx < 2048; idx += 256) {
    int r = idx >> 4, c8 = (idx & 15) * 8;
    *(int4*)&Bs[r * LW + c8] = *(const int4*)&WcatL[(view * 128 + r) * 128 + c8];
  }
  __syncthreads();

  int w = tid >> 6, lane = tid & 63;
  int wr = (w >> 1) * 64, wc = (w & 1) * 64;
  int lrow = lane & 15, quad = lane >> 4;

  f32x4 acc[4][4];
#pragma unroll
  for (int mi = 0; mi < 4; ++mi)
#pragma unroll
    for (int ni = 0; ni < 4; ++ni) acc[mi][ni] = (f32x4){0.f, 0.f, 0.f, 0.f};

#pragma unroll
  for (int k0 = 0; k0 < 128; k0 += 32) {
    bf16x8 a[4], b[4];
#pragma unroll
    for (int mi = 0; mi < 4; ++mi)
      a[mi] = *(const bf16x8*)&As[(wr + mi * 16 + lrow) * LW + k0 + quad * 8];
#pragma unroll
    for (int ni = 0; ni < 4; ++ni)
      b[ni] = *(const bf16x8*)&Bs[(wc + ni * 16 + lrow) * LW + k0 + quad * 8];
#pragma unroll
    for (int mi = 0; mi < 4; ++mi)
#pragma unroll
      for (int ni = 0; ni < 4; ++ni)
        acc[mi][ni] = __builtin_amdgcn_mfma_f32_16x16x32_bf16(a[mi], b[ni], acc[mi][ni], 0, 0, 0);
  }

  short* out = tAll + (size_t)view * ((size_t)NN * 128);
#pragma unroll
  for (int mi = 0; mi < 4; ++mi) {
#pragma unroll
    for (int ni = 0; ni < 4; ++ni) {
#pragma unroll
      for (int r = 0; r < 4; ++r) {
        int row = rowbase + wr + mi * 16 + quad * 4 + r;
        if (row < NN) {
          int col = wc + ni * 16 + lrow;
          out[(size_t)row * 128 + col] = f2bf(acc[mi][ni][r]);
        }
      }
    }
  }
}

// ---------------- gather-aggregate + combine + residual + leaky_relu ----------------
// one wave per node; coalesced edge-record preload + shfl broadcast
__global__ __launch_bounds__(256) void agg_kernel(
    const short* __restrict__ tAll, const int2* __restrict__ csrE,
    const int* __restrict__ offs, const short* __restrict__ h_prev,
    const float* __restrict__ b_mi, const float* __restrict__ b_mo,
    const float* __restrict__ b_si, const float* __restrict__ b_so,
    const float* __restrict__ b_u, const float* __restrict__ Cin,
    const float* __restrict__ Cout, const float* __restrict__ Call,
    const float* __restrict__ cst, short* __restrict__ h_out) {
  int gid = blockIdx.x * 256 + threadIdx.x;
  int v = gid >> 6;
  int lane = gid & 63;
  int f0 = lane * 2;
  float ax[3], ay[3];

#pragma unroll
  for (int view = 0; view < 3; ++view) {
    const short* t = tAll + (size_t)view * ((size_t)NN * 128);
    int s = offs[view * NN + v];
    int e = offs[view * NN + v + 1];
    float accx = 0.f, accy = 0.f;
    for (int base = s; base < e; base += 64) {
      int cnt = e - base; if (cnt > 64) cnt = 64;
      int rx = 0, ry = 0;
      if (lane < cnt) {
        int2 rec = csrE[base + lane];
        rx = rec.x; ry = rec.y;
      }
      int j = 0;
      for (; j + 3 < cnt; j += 4) {
        int s0 = __shfl(rx, j), s1 = __shfl(rx, j + 1);
        int s2 = __shfl(rx, j + 2), s3 = __shfl(rx, j + 3);
        float w0 = __int_as_float(__shfl(ry, j));
        float w1 = __int_as_float(__shfl(ry, j + 1));
        float w2 = __int_as_float(__shfl(ry, j + 2));
        float w3 = __int_as_float(__shfl(ry, j + 3));
        unsigned u0 = *(const unsigned*)&t[(size_t)s0 * 128 + f0];
        unsigned u1 = *(const unsigned*)&t[(size_t)s1 * 128 + f0];
        unsigned u2 = *(const unsigned*)&t[(size_t)s2 * 128 + f0];
        unsigned u3 = *(const unsigned*)&t[(size_t)s3 * 128 + f0];
        accx += w0 * bf_lo(u0) + w1 * bf_lo(u1) + w2 * bf_lo(u2) + w3 * bf_lo(u3);
        accy += w0 * bf_hi(u0) + w1 * bf_hi(u1) + w2 * bf_hi(u2) + w3 * bf_hi(u3);
      }
      for (; j < cnt; ++j) {
        int s0 = __shfl(rx, j);
        float w0 = __int_as_float(__shfl(ry, j));
        unsigned u0 = *(const unsigned*)&t[(size_t)s0 * 128 + f0];
        accx += w0 * bf_lo(u0);
        accy += w0 * bf_hi(u0);
      }
    }
    ax[view] = accx; ay[view] = accy;
  }

  float ci = Cin[v], co = Cout[v], ca = Call[v];
  float2 bi = *(const float2*)&b_mi[f0];
  float2 bsi2 = *(const float2*)&b_si[f0];
  float2 bo = *(const float2*)&b_mo[f0];
  float2 bso2 = *(const float2*)&b_so[f0];
  float2 bu = *(const float2*)&b_u[f0];
  float2 cs = *(const float2*)&cst[(size_t)v * 128 + f0];
  unsigned hp = *(const unsigned*)&h_prev[(size_t)v * 128 + f0];

  float gx = ca * (ax[2] + bu.x) + ci * (ax[0] + bi.x + bsi2.x) +
             co * (ax[1] + bo.x + bso2.x) + cs.x + bf_lo(hp);
  float gy = ca * (ay[2] + bu.y) + ci * (ay[0] + bi.y + bsi2.y) +
             co * (ay[1] + bo.y + bso2.y) + cs.y + bf_hi(hp);
  gx = gx > 0.f ? gx : 0.01f * gx;
  gy = gy > 0.f ? gy : 0.01f * gy;
  *(unsigned*)&h_out[(size_t)v * 128 + f0] = pack2(gx, gy);
}

// ---------------- fused decoder ----------------
__global__ __launch_bounds__(256) void dec_kernel(const short* __restrict__ h,
                                                  const float* __restrict__ Wd1,
                                                  const float* __restrict__ bd1,
                                                  const float* __restrict__ Wd2,
                                                  const float* __restrict__ bd2,
                                                  float* __restrict__ out_logp,
                                                  float* __restrict__ out_emb) {
  __shared__ float Hs[32 * 128];
  __shared__ float W1t[64 * 66];
  __shared__ float W2t[64 * 66];
  __shared__ float Zs[32 * 68];
  int tid = threadIdx.x;
  int base = blockIdx.x * 32;

  for (int idx = tid; idx < 2048; idx += 256) {
    unsigned u = *(const unsigned*)&h[(size_t)base * 128 + idx * 2];
    Hs[idx * 2] = bf_lo(u);
    Hs[idx * 2 + 1] = bf_hi(u);
  }
  for (int idx = tid; idx < 4096; idx += 256) {
    int c = idx >> 6, k = idx & 63;
    W2t[k * 66 + c] = Wd2[idx];
  }

  int j = tid & 63;
  int rg = tid >> 6;
  float zacc[8];
#pragma unroll
  for (int r = 0; r < 8; ++r) zacc[r] = 0.f;

  for (int kk = 0; kk < 128; kk += 64) {
    __syncthreads();
    for (int idx = tid; idx < 4096; idx += 256) {
      int jj = idx >> 6, k = idx & 63;
      W1t[k * 66 + jj] = Wd1[jj * 128 + kk + k];
    }
    __syncthreads();
    for (int k = 0; k < 64; ++k) {
      float w = W1t[k * 66 + j];
#pragma unroll
      for (int r = 0; r < 8; ++r) zacc[r] += Hs[(rg * 8 + r) * 128 + kk + k] * w;
    }
  }
  float b1 = bd1[j];
#pragma unroll
  for (int r = 0; r < 8; ++r) {
    float z = zacc[r] + b1;
    Zs[(rg * 8 + r) * 68 + j] = z > 0.f ? z : 0.f;
  }
  __syncthreads();

  float b2 = bd2[j];
  float lg[8];
#pragma unroll
  for (int i = 0; i < 8; ++i) lg[i] = b2;
  for (int k = 0; k < 64; ++k) {
    float w = W2t[k * 66 + j];
#pragma unroll
    for (int i = 0; i < 8; ++i) lg[i] += Zs[(rg + 4 * i) * 68 + k] * w;
  }

#pragma unroll
  for (int i = 0; i < 8; ++i) {
    float m = lg[i];
    for (int d = 1; d < 64; d <<= 1) m = fmaxf(m, __shfl_xor(m, d));
    float s = expf(lg[i] - m);
    for (int d = 1; d < 64; d <<= 1) s += __shfl_xor(s, d);
    float lp = lg[i] - m - logf(s);
    out_logp[(size_t)(base + rg + 4 * i) * 64 + j] = lp;
  }

#pragma unroll
  for (int i = 0; i < 8; ++i) {
    int r = rg + 4 * i;
    float v1 = Hs[r * 128 + j];
    float v2 = Hs[r * 128 + 64 + j];
    float ss = v1 * v1 + v2 * v2;
    for (int d = 1; d < 64; d <<= 1) ss += __shfl_xor(ss, d);
    float nrm = sqrtf(ss);
    float sc = 1.f / fmaxf(nrm, 1e-12f);
    size_t o = (size_t)(base + r) * 128;
    out_emb[o + j] = v1 * sc;
    out_emb[o + 64 + j] = v2 * sc;
  }
}

extern "C" void kernel_launch(void* const* d_in, const int* in_sizes, int n_in,
                              void* d_out, int out_size, void* d_ws, size_t ws_size,
                              hipStream_t stream) {
  const float* x   = (const float*)d_in[0];
  const int* eiI   = (const int*)d_in[1];
  const float* ewI = (const float*)d_in[2];
  const int* eiO   = (const int*)d_in[3];
  const float* ewO = (const float*)d_in[4];
  const int* eiU   = (const int*)d_in[5];
  const float* ewU = (const float*)d_in[6];
  const float* pe  = (const float*)d_in[7];
  const float* Wmi = (const float*)d_in[8];
  const float* Wmo = (const float*)d_in[9];
  const float* Wsh = (const float*)d_in[10];
  const float* Wu  = (const float*)d_in[11];
  const float* bmi = (const float*)d_in[12];
  const float* bmo = (const float*)d_in[13];
  const float* bsi = (const float*)d_in[14];
  const float* bso = (const float*)d_in[15];
  const float* bu  = (const float*)d_in[16];
  const float* Cin = (const float*)d_in[17];
  const float* Cou = (const float*)d_in[18];
  const float* Cal = (const float*)d_in[19];
  const float* cst = (const float*)d_in[20];
  const float* Wd1 = (const float*)d_in[21];
  const float* bd1 = (const float*)d_in[22];
  const float* Wd2 = (const float*)d_in[23];
  const float* bd2 = (const float*)d_in[24];

  const size_t ND = (size_t)NN * DD;   // 12,800,000
  short* wsS = (short*)d_ws;
  short* hA   = wsS;                    // ND shorts
  short* hB   = hA + ND;                // ND
  short* tAll = hB + ND;                // 3*ND
  short* Wcat = tAll + 3 * ND;          // 98304 (keeps csrE 8B-aligned)
  int2* csrE  = (int2*)(Wcat + 98304);  // 3E records
  int* counts = (int*)(csrE + (size_t)3 * EE); // 3N
  int* offs   = counts + 3 * NN;        // 3N+1
  int* work   = offs + 3 * NN + 4;      // 3N+1
  int* bsums  = work + 3 * NN + 4;

  hipMemsetAsync(counts, 0, (size_t)3 * NN * sizeof(int), stream);

  pe_kernel<<<6250, 256, 0, stream>>>(x, pe, hA);
  wprep_kernel<<<384, 256, 0, stream>>>(Wmi, Wmo, Wsh, Wu, Wcat);
  hist_kernel<<<(3 * EE + 255) / 256, 256, 0, stream>>>(eiI, eiO, eiU, counts);
  const int nb1 = (3 * NN + 1023) / 1024;  // 293
  scan1_kernel<<<nb1, 256, 0, stream>>>(counts, offs, bsums);
  scan2_kernel<<<1, 512, 0, stream>>>(bsums, nb1);
  scan3_kernel<<<(3 * NN + 255) / 256, 256, 0, stream>>>(offs, work, bsums);
  fill_kernel<<<(3 * EE + 255) / 256, 256, 0, stream>>>(eiI, eiO, eiU, ewI, ewO, ewU,
                                                        work, csrE);

  const short* hin = hA;
  short* hout = hB;
  dim3 mmGrid((NN + 127) / 128, 3);  // (782, 3)
  for (int l = 0; l < 2; ++l) {
    mm_mfma<<<mmGrid, 256, 0, stream>>>(hin, Wcat + l * 49152, tAll);
    agg_kernel<<<25000, 256, 0, stream>>>(tAll, csrE, offs, hin,
                                          bmi + l * DD, bmo + l * DD, bsi + l * DD,
                                          bso + l * DD, bu + l * DD, Cin + l * NN,
                                          Cou + l * NN, Cal + l * NN,
                                          cst + (size_t)l * NN * DD, hout);
    short* tmp = (short*)hin;
    hin = hout;
    hout = tmp;
  }

  float* out_logp = (float*)d_out;
  float* out_emb = out_logp + (size_t)NN * CLS;
  dec_kernel<<<3125, 256, 0, stream>>>(hin, Wd1, bd1, Wd2, bd2, out_logp, out_emb);
}

// Round 4
// 805.477 us; speedup vs baseline: 2.4850x; 1.3165x over previous
//
#include <hip/hip_runtime.h>
#include <math.h>

#define NN 100000
#define EE 1000000
#define DD 128
#define CLS 64

#define NB 196        // destination buckets per view (512 nodes each)
#define CHUNK 4096    // edges per partition workgroup
#define NCH 245       // ceil(EE / CHUNK)
#define SLOTS (3 * NB * NCH)   // 144060
#define CAPB 8192     // LDS record cache in buildB

typedef short bf16x8 __attribute__((ext_vector_type(8)));
typedef float f32x4 __attribute__((ext_vector_type(4)));

static __device__ __forceinline__ short f2bf(float f) {
  union { float f; unsigned u; } v; v.f = f;
  unsigned r = v.u + 0x7FFF + ((v.u >> 16) & 1);   // RNE
  return (short)(r >> 16);
}
static __device__ __forceinline__ unsigned pack2(float a, float b) {
  return ((unsigned)(unsigned short)f2bf(b) << 16) | (unsigned short)f2bf(a);
}
static __device__ __forceinline__ float bf_lo(unsigned u) {
  union { unsigned u; float f; } v; v.u = u << 16; return v.f;
}
static __device__ __forceinline__ float bf_hi(unsigned u) {
  union { unsigned u; float f; } v; v.u = u & 0xffff0000u; return v.f;
}

// ---------------- PE add: h = bf16(x + pe), 8 elems/thread ----------------
__global__ __launch_bounds__(256) void pe_kernel(const float* __restrict__ x,
                                                 const float* __restrict__ pe,
                                                 short* __restrict__ h) {
  int idx8 = blockIdx.x * 256 + threadIdx.x;   // grid 6250 -> 1.6M exact
  int d0 = (idx8 & 15) * 8;
  float4 a = *(const float4*)&x[(size_t)idx8 * 8];
  float4 b = *(const float4*)&x[(size_t)idx8 * 8 + 4];
  float4 pa = *(const float4*)&pe[d0];
  float4 pb = *(const float4*)&pe[d0 + 4];
  int4 o;
  o.x = pack2(a.x + pa.x, a.y + pa.y);
  o.y = pack2(a.z + pa.z, a.w + pa.w);
  o.z = pack2(b.x + pb.x, b.y + pb.y);
  o.w = pack2(b.z + pb.z, b.w + pb.w);
  *(int4*)&h[(size_t)idx8 * 8] = o;
}

// ---------------- weight prep ----------------
__global__ __launch_bounds__(256) void wprep_kernel(const float* __restrict__ Wmi,
                                                    const float* __restrict__ Wmo,
                                                    const float* __restrict__ Wsh,
                                                    const float* __restrict__ Wu,
                                                    short* __restrict__ Wcat) {
  int idx = blockIdx.x * 256 + threadIdx.x;   // grid 384 -> 98304 exact
  int l = idx / 49152;
  int r = idx - l * 49152;
  int j = r >> 7, k = r & 127;
  float v;
  if (j < 128)      v = Wmi[l*16384 + j*128 + k] + Wsh[l*16384 + j*128 + k];
  else if (j < 256) v = Wmo[l*16384 + (j-128)*128 + k] + Wsh[l*16384 + (j-128)*128 + k];
  else              v = Wu[l*16384 + (j-256)*128 + k];
  Wcat[idx] = f2bf(v);
}

// ---------------- partition phase A: per-chunk bucket histogram ----------------
__global__ __launch_bounds__(256) void countA_kernel(const int* __restrict__ ei0,
                                                     const int* __restrict__ ei1,
                                                     const int* __restrict__ ei2,
                                                     int* __restrict__ counts) {
  __shared__ int c[NB];
  int v = blockIdx.y, ch = blockIdx.x, tid = threadIdx.x;
  const int* dstp = ((v == 0) ? ei0 : (v == 1) ? ei1 : ei2) + EE;
  for (int i = tid; i < NB; i += 256) c[i] = 0;
  __syncthreads();
  int s = ch * CHUNK, e = (s + CHUNK < EE) ? s + CHUNK : EE;
  for (int i = s + tid; i < e; i += 256) atomicAdd(&c[dstp[i] >> 9], 1);
  __syncthreads();
  for (int b = tid; b < NB; b += 256) counts[(v * NB + b) * NCH + ch] = c[b];
}

// ---------------- scan (generalized length n) ----------------
__global__ __launch_bounds__(256) void scan1_kernel(const int* __restrict__ counts,
                                                    int* __restrict__ S,
                                                    int* __restrict__ bsums, int n) {
  __shared__ int sd[256];
  int t = threadIdx.x;
  int base = blockIdx.x * 1024 + t * 4;
  int4 v = make_int4(0, 0, 0, 0);
  if (base + 3 < n) {
    v = *(const int4*)&counts[base];
  } else {
    if (base + 0 < n) v.x = counts[base + 0];
    if (base + 1 < n) v.y = counts[base + 1];
    if (base + 2 < n) v.z = counts[base + 2];
    if (base + 3 < n) v.w = counts[base + 3];
  }
  int ts = v.x + v.y + v.z + v.w;
  sd[t] = ts;
  __syncthreads();
  for (int off = 1; off < 256; off <<= 1) {
    int xel = (t >= off) ? sd[t - off] : 0;
    __syncthreads();
    sd[t] += xel;
    __syncthreads();
  }
  int excl = sd[t] - ts;
  int o0 = excl, o1 = o0 + v.x, o2 = o1 + v.y, o3 = o2 + v.z;
  if (base + 0 < n) S[base + 0] = o0;
  if (base + 1 < n) S[base + 1] = o1;
  if (base + 2 < n) S[base + 2] = o2;
  if (base + 3 < n) S[base + 3] = o3;
  if (t == 255) bsums[blockIdx.x] = sd[255];
}

__global__ void scan2_kernel(int* __restrict__ bsums, int nb) {
  __shared__ int sd[512];
  int t = threadIdx.x;
  int v = (t < nb) ? bsums[t] : 0;
  sd[t] = v;
  __syncthreads();
  for (int off = 1; off < 512; off <<= 1) {
    int xel = (t >= off) ? sd[t - off] : 0;
    __syncthreads();
    sd[t] += xel;
    __syncthreads();
  }
  if (t < nb) bsums[t] = sd[t] - v;
}

__global__ __launch_bounds__(256) void scan3_kernel(int* __restrict__ S,
                                                    const int* __restrict__ bsums, int n) {
  int i = blockIdx.x * 256 + threadIdx.x;
  if (i < n) S[i] += bsums[i >> 10];
}

// ---------------- partition phase A: scatter into bucket-major runs ----------------
__global__ __launch_bounds__(256) void partA_kernel(const int* __restrict__ ei0,
                                                    const int* __restrict__ ei1,
                                                    const int* __restrict__ ei2,
                                                    const float* __restrict__ ew0,
                                                    const float* __restrict__ ew1,
                                                    const float* __restrict__ ew2,
                                                    const int* __restrict__ S,
                                                    int2* __restrict__ binned) {
  __shared__ int cur[NB];
  int v = blockIdx.y, ch = blockIdx.x, tid = threadIdx.x;
  const int* ei = (v == 0) ? ei0 : (v == 1) ? ei1 : ei2;
  const float* ew = (v == 0) ? ew0 : (v == 1) ? ew1 : ew2;
  for (int b = tid; b < NB; b += 256) cur[b] = S[(v * NB + b) * NCH + ch];
  __syncthreads();
  int s = ch * CHUNK, e = (s + CHUNK < EE) ? s + CHUNK : EE;
  for (int i = s + tid; i < e; i += 256) {
    int src = ei[i];
    int dst = ei[EE + i];
    float w = ew[i];
    int b = dst >> 9;
    int pos = atomicAdd(&cur[b], 1);
    binned[pos] = make_int2(src | ((dst & 511) << 17), __float_as_int(w));
  }
}

// ---------------- phase B: per-bucket local CSR + offs ----------------
__global__ __launch_bounds__(256) void buildB_kernel(const int2* __restrict__ binned,
                                                     const int* __restrict__ S,
                                                     unsigned* __restrict__ csr4,
                                                     int* __restrict__ offs) {
  __shared__ int2 recs[CAPB];   // 64 KB
  __shared__ int cnt[512];
  __shared__ int pref[512];
  __shared__ int sd[256];
  int gb = blockIdx.x, tid = threadIdx.x;
  int v = gb / NB, b = gb - v * NB;
  int base = S[gb * NCH];
  int next = (gb == 3 * NB - 1) ? 3 * EE : S[(gb + 1) * NCH];
  int n = next - base;
  for (int i = tid; i < 512; i += 256) cnt[i] = 0;
  int m = n < CAPB ? n : CAPB;
  for (int i = tid; i < m; i += 256) recs[i] = binned[base + i];
  __syncthreads();
  for (int i = tid; i < n; i += 256) {
    int2 r = (i < CAPB) ? recs[i] : binned[base + i];
    atomicAdd(&cnt[(r.x >> 17) & 511], 1);
  }
  __syncthreads();
  // exclusive scan over 512 with 256 threads (pairwise + Hillis-Steele)
  int c0 = cnt[2 * tid], c1 = cnt[2 * tid + 1];
  int ssum = c0 + c1;
  sd[tid] = ssum;
  __syncthreads();
  for (int off = 1; off < 256; off <<= 1) {
    int x = (tid >= off) ? sd[tid - off] : 0;
    __syncthreads();
    sd[tid] += x;
    __syncthreads();
  }
  int excl = sd[tid] - ssum;
  pref[2 * tid] = excl;
  pref[2 * tid + 1] = excl + c0;
  __syncthreads();
  int node0 = b * 512;
  for (int i = tid; i < 512; i += 256) {
    int node = node0 + i;
    if (node < NN) offs[v * NN + node] = base + pref[i];
  }
  if (gb == 0 && tid == 0) offs[3 * NN] = 3 * EE;
  for (int i = tid; i < 512; i += 256) cnt[i] = pref[i];   // cursors
  __syncthreads();
  for (int i = tid; i < n; i += 256) {
    int2 r = (i < CAPB) ? recs[i] : binned[base + i];
    int nl = (r.x >> 17) & 511;
    int p = atomicAdd(&cnt[nl], 1);
    float w = __int_as_float(r.y);
    unsigned wb = (unsigned)(unsigned short)f2bf(w);   // positive -> 15 bits
    csr4[base + p] = (wb << 17) | (unsigned)(r.x & 0x1FFFF);
  }
}

// ---------------- fused 3-view GEMM via bf16 MFMA ----------------
#define LW 136
__global__ __launch_bounds__(256) void mm_mfma(const short* __restrict__ H,
                                               const short* __restrict__ WcatL,
                                               short* __restrict__ tAll) {
  __shared__ short As[128 * LW];
  __shared__ short Bs[128 * LW];
  int tid = threadIdx.x;
  int rowbase = blockIdx.x * 128;
  int view = blockIdx.y;

  for (int idx = tid; idx < 2048; idx += 256) {
    int r = idx >> 4, c8 = (idx & 15) * 8;
    int gr = rowbase + r; if (gr >= NN) gr = NN - 1;
    *(int4*)&As[r * LW + c8] = *(const int4*)&H[(size_t)gr * 128 + c8];
  }
  for (int idx = tid; idx < 2048; idx += 256) {
    int r = idx >> 4, c8 = (idx & 15) * 8;
    *(int4*)&Bs[r * LW + c8] = *(const int4*)&WcatL[(view * 128 + r) * 128 + c8];
  }
  __syncthreads();

  int w = tid >> 6, lane = tid & 63;
  int wr = (w >> 1) * 64, wc = (w & 1) * 64;
  int lrow = lane & 15, quad = lane >> 4;

  f32x4 acc[4][4];
#pragma unroll
  for (int mi = 0; mi < 4; ++mi)
#pragma unroll
    for (int ni = 0; ni < 4; ++ni) acc[mi][ni] = (f32x4){0.f, 0.f, 0.f, 0.f};

#pragma unroll
  for (int k0 = 0; k0 < 128; k0 += 32) {
    bf16x8 a[4], b[4];
#pragma unroll
    for (int mi = 0; mi < 4; ++mi)
      a[mi] = *(const bf16x8*)&As[(wr + mi * 16 + lrow) * LW + k0 + quad * 8];
#pragma unroll
    for (int ni = 0; ni < 4; ++ni)
      b[ni] = *(const bf16x8*)&Bs[(wc + ni * 16 + lrow) * LW + k0 + quad * 8];
#pragma unroll
    for (int mi = 0; mi < 4; ++mi)
#pragma unroll
      for (int ni = 0; ni < 4; ++ni)
        acc[mi][ni] = __builtin_amdgcn_mfma_f32_16x16x32_bf16(a[mi], b[ni], acc[mi][ni], 0, 0, 0);
  }

  short* out = tAll + (size_t)view * ((size_t)NN * 128);
#pragma unroll
  for (int mi = 0; mi < 4; ++mi) {
#pragma unroll
    for (int ni = 0; ni < 4; ++ni) {
#pragma unroll
      for (int r = 0; r < 4; ++r) {
        int row = rowbase + wr + mi * 16 + quad * 4 + r;
        if (row < NN) {
          int col = wc + ni * 16 + lrow;
          out[(size_t)row * 128 + col] = f2bf(acc[mi][ni][r]);
        }
      }
    }
  }
}

// ---------------- gather-aggregate + combine + residual + leaky_relu ----------------
// one wave per node; coalesced 4B record preload + single shfl broadcast per edge
__global__ __launch_bounds__(256) void agg_kernel(
    const short* __restrict__ tAll, const unsigned* __restrict__ csr4,
    const int* __restrict__ offs, const short* __restrict__ h_prev,
    const float* __restrict__ b_mi, const float* __restrict__ b_mo,
    const float* __restrict__ b_si, const float* __restrict__ b_so,
    const float* __restrict__ b_u, const float* __restrict__ Cin,
    const float* __restrict__ Cout, const float* __restrict__ Call,
    const float* __restrict__ cst, short* __restrict__ h_out) {
  int gid = blockIdx.x * 256 + threadIdx.x;
  int v = gid >> 6;
  int lane = gid & 63;
  int f0 = lane * 2;
  float ax[3], ay[3];

#pragma unroll
  for (int view = 0; view < 3; ++view) {
    const short* t = tAll + (size_t)view * ((size_t)NN * 128);
    int s = offs[view * NN + v];
    int e = offs[view * NN + v + 1];
    float accx = 0.f, accy = 0.f;
    for (int base = s; base < e; base += 64) {
      int cnt = e - base; if (cnt > 64) cnt = 64;
      int r = 0;
      if (lane < cnt) r = (int)csr4[base + lane];
      int j = 0;
      for (; j + 3 < cnt; j += 4) {
        unsigned r0 = (unsigned)__shfl(r, j);
        unsigned r1 = (unsigned)__shfl(r, j + 1);
        unsigned r2 = (unsigned)__shfl(r, j + 2);
        unsigned r3 = (unsigned)__shfl(r, j + 3);
        float w0 = __uint_as_float((r0 >> 17) << 16);
        float w1 = __uint_as_float((r1 >> 17) << 16);
        float w2 = __uint_as_float((r2 >> 17) << 16);
        float w3 = __uint_as_float((r3 >> 17) << 16);
        unsigned u0 = *(const unsigned*)&t[(size_t)(r0 & 0x1FFFF) * 128 + f0];
        unsigned u1 = *(const unsigned*)&t[(size_t)(r1 & 0x1FFFF) * 128 + f0];
        unsigned u2 = *(const unsigned*)&t[(size_t)(r2 & 0x1FFFF) * 128 + f0];
        unsigned u3 = *(const unsigned*)&t[(size_t)(r3 & 0x1FFFF) * 128 + f0];
        accx += w0 * bf_lo(u0) + w1 * bf_lo(u1) + w2 * bf_lo(u2) + w3 * bf_lo(u3);
        accy += w0 * bf_hi(u0) + w1 * bf_hi(u1) + w2 * bf_hi(u2) + w3 * bf_hi(u3);
      }
      for (; j < cnt; ++j) {
        unsigned r0 = (unsigned)__shfl(r, j);
        float w0 = __uint_as_float((r0 >> 17) << 16);
        unsigned u0 = *(const unsigned*)&t[(size_t)(r0 & 0x1FFFF) * 128 + f0];
        accx += w0 * bf_lo(u0);
        accy += w0 * bf_hi(u0);
      }
    }
    ax[view] = accx; ay[view] = accy;
  }

  float ci = Cin[v], co = Cout[v], ca = Call[v];
  float2 bi = *(const float2*)&b_mi[f0];
  float2 bsi2 = *(const float2*)&b_si[f0];
  float2 bo = *(const float2*)&b_mo[f0];
  float2 bso2 = *(const float2*)&b_so[f0];
  float2 bu = *(const float2*)&b_u[f0];
  float2 cs = *(const float2*)&cst[(size_t)v * 128 + f0];
  unsigned hp = *(const unsigned*)&h_prev[(size_t)v * 128 + f0];

  float gx = ca * (ax[2] + bu.x) + ci * (ax[0] + bi.x + bsi2.x) +
             co * (ax[1] + bo.x + bso2.x) + cs.x + bf_lo(hp);
  float gy = ca * (ay[2] + bu.y) + ci * (ay[0] + bi.y + bsi2.y) +
             co * (ay[1] + bo.y + bso2.y) + cs.y + bf_hi(hp);
  gx = gx > 0.f ? gx : 0.01f * gx;
  gy = gy > 0.f ? gy : 0.01f * gy;
  *(unsigned*)&h_out[(size_t)v * 128 + f0] = pack2(gx, gy);
}

// ---------------- fused decoder ----------------
__global__ __launch_bounds__(256) void dec_kernel(const short* __restrict__ h,
                                                  const float* __restrict__ Wd1,
                                                  const float* __restrict__ bd1,
                                                  const float* __restrict__ Wd2,
                                                  const float* __restrict__ bd2,
                                                  float* __restrict__ out_logp,
                                                  float* __restrict__ out_emb) {
  __shared__ float Hs[32 * 128];
  __shared__ float W1t[64 * 66];
  __shared__ float W2t[64 * 66];
  __shared__ float Zs[32 * 68];
  int tid = threadIdx.x;
  int base = blockIdx.x * 32;

  for (int idx = tid; idx < 2048; idx += 256) {
    unsigned u = *(const unsigned*)&h[(size_t)base * 128 + idx * 2];
    Hs[idx * 2] = bf_lo(u);
    Hs[idx * 2 + 1] = bf_hi(u);
  }
  for (int idx = tid; idx < 4096; idx += 256) {
    int c = idx >> 6, k = idx & 63;
    W2t[k * 66 + c] = Wd2[idx];
  }

  int j = tid & 63;
  int rg = tid >> 6;
  float zacc[8];
#pragma unroll
  for (int r = 0; r < 8; ++r) zacc[r] = 0.f;

  for (int kk = 0; kk < 128; kk += 64) {
    __syncthreads();
    for (int idx = tid; idx < 4096; idx += 256) {
      int jj = idx >> 6, k = idx & 63;
      W1t[k * 66 + jj] = Wd1[jj * 128 + kk + k];
    }
    __syncthreads();
    for (int k = 0; k < 64; ++k) {
      float w = W1t[k * 66 + j];
#pragma unroll
      for (int r = 0; r < 8; ++r) zacc[r] += Hs[(rg * 8 + r) * 128 + kk + k] * w;
    }
  }
  float b1 = bd1[j];
#pragma unroll
  for (int r = 0; r < 8; ++r) {
    float z = zacc[r] + b1;
    Zs[(rg * 8 + r) * 68 + j] = z > 0.f ? z : 0.f;
  }
  __syncthreads();

  float b2 = bd2[j];
  float lg[8];
#pragma unroll
  for (int i = 0; i < 8; ++i) lg[i] = b2;
  for (int k = 0; k < 64; ++k) {
    float w = W2t[k * 66 + j];
#pragma unroll
    for (int i = 0; i < 8; ++i) lg[i] += Zs[(rg + 4 * i) * 68 + k] * w;
  }

#pragma unroll
  for (int i = 0; i < 8; ++i) {
    float m = lg[i];
    for (int d = 1; d < 64; d <<= 1) m = fmaxf(m, __shfl_xor(m, d));
    float s = expf(lg[i] - m);
    for (int d = 1; d < 64; d <<= 1) s += __shfl_xor(s, d);
    float lp = lg[i] - m - logf(s);
    out_logp[(size_t)(base + rg + 4 * i) * 64 + j] = lp;
  }

#pragma unroll
  for (int i = 0; i < 8; ++i) {
    int r = rg + 4 * i;
    float v1 = Hs[r * 128 + j];
    float v2 = Hs[r * 128 + 64 + j];
    float ss = v1 * v1 + v2 * v2;
    for (int d = 1; d < 64; d <<= 1) ss += __shfl_xor(ss, d);
    float nrm = sqrtf(ss);
    float sc = 1.f / fmaxf(nrm, 1e-12f);
    size_t o = (size_t)(base + r) * 128;
    out_emb[o + j] = v1 * sc;
    out_emb[o + 64 + j] = v2 * sc;
  }
}

extern "C" void kernel_launch(void* const* d_in, const int* in_sizes, int n_in,
                              void* d_out, int out_size, void* d_ws, size_t ws_size,
                              hipStream_t stream) {
  const float* x   = (const float*)d_in[0];
  const int* eiI   = (const int*)d_in[1];
  const float* ewI = (const float*)d_in[2];
  const int* eiO   = (const int*)d_in[3];
  const float* ewO = (const float*)d_in[4];
  const int* eiU   = (const int*)d_in[5];
  const float* ewU = (const float*)d_in[6];
  const float* pe  = (const float*)d_in[7];
  const float* Wmi = (const float*)d_in[8];
  const float* Wmo = (const float*)d_in[9];
  const float* Wsh = (const float*)d_in[10];
  const float* Wu  = (const float*)d_in[11];
  const float* bmi = (const float*)d_in[12];
  const float* bmo = (const float*)d_in[13];
  const float* bsi = (const float*)d_in[14];
  const float* bso = (const float*)d_in[15];
  const float* bu  = (const float*)d_in[16];
  const float* Cin = (const float*)d_in[17];
  const float* Cou = (const float*)d_in[18];
  const float* Cal = (const float*)d_in[19];
  const float* cst = (const float*)d_in[20];
  const float* Wd1 = (const float*)d_in[21];
  const float* bd1 = (const float*)d_in[22];
  const float* Wd2 = (const float*)d_in[23];
  const float* bd2 = (const float*)d_in[24];

  const size_t ND = (size_t)NN * DD;   // 12,800,000
  short* wsS = (short*)d_ws;
  short* hA   = wsS;                    // ND shorts
  short* hB   = hA + ND;                // ND
  short* tAll = hB + ND;                // 3*ND
  short* Wcat = tAll + 3 * ND;          // 98304 shorts (total so far = even # shorts)
  int2* binned   = (int2*)(Wcat + 98304);          // 3E int2 (24 MB)
  unsigned* csr4 = (unsigned*)(binned + (size_t)3 * EE); // 3E uint (12 MB)
  int* S      = (int*)(csr4 + (size_t)3 * EE);     // SLOTS ints
  int* bsums  = S + SLOTS + 4;                     // scan block sums (<=512)
  int* offs   = bsums + 512;                       // 3N+1

  pe_kernel<<<6250, 256, 0, stream>>>(x, pe, hA);
  wprep_kernel<<<384, 256, 0, stream>>>(Wmi, Wmo, Wsh, Wu, Wcat);

  dim3 chGrid(NCH, 3);
  countA_kernel<<<chGrid, 256, 0, stream>>>(eiI, eiO, eiU, S);   // S holds raw counts first
  const int nb1 = (SLOTS + 1023) / 1024;   // 141
  scan1_kernel<<<nb1, 256, 0, stream>>>(S, S, bsums, SLOTS);     // in-place exclusive (block-local)
  scan2_kernel<<<1, 512, 0, stream>>>(bsums, nb1);
  scan3_kernel<<<(SLOTS + 255) / 256, 256, 0, stream>>>(S, bsums, SLOTS);
  partA_kernel<<<chGrid, 256, 0, stream>>>(eiI, eiO, eiU, ewI, ewO, ewU, S, binned);
  buildB_kernel<<<3 * NB, 256, 0, stream>>>(binned, S, csr4, offs);

  const short* hin = hA;
  short* hout = hB;
  dim3 mmGrid((NN + 127) / 128, 3);  // (782, 3)
  for (int l = 0; l < 2; ++l) {
    mm_mfma<<<mmGrid, 256, 0, stream>>>(hin, Wcat + l * 49152, tAll);
    agg_kernel<<<25000, 256, 0, stream>>>(tAll, csr4, offs, hin,
                                          bmi + l * DD, bmo + l * DD, bsi + l * DD,
                                          bso + l * DD, bu + l * DD, Cin + l * NN,
                                          Cou + l * NN, Cal + l * NN,
                                          cst + (size_t)l * NN * DD, hout);
    short* tmp = (short*)hin;
    hin = hout;
    hout = tmp;
  }

  float* out_logp = (float*)d_out;
  float* out_emb = out_logp + (size_t)NN * CLS;
  dec_kernel<<<3125, 256, 0, stream>>>(hin, Wd1, bd1, Wd2, bd2, out_logp, out_emb);
}